// Round 8
// baseline (250.209 us; speedup 1.0000x reference)
//
#include <hip/hip_runtime.h>

// DB4 analysis low-pass h; high-pass g[n] = (-1)^n h[7-n]
#define H0 0.2303778133088964f
#define H1 0.7148465705529155f
#define H2 0.6308807679298587f
#define H3 (-0.027983769416859854f)
#define H4 (-0.18703481171888114f)
#define H5 0.030841381835986965f
#define H6 0.032883011666982945f
#define H7 (-0.010597401785069032f)

// Tile: 64 wide x 32 tall. Grid (8,16,96) = 12288 blocks.
// Workspace: pmn[12288], pmx[12288].
//
// LDS layout (bytes), lifetime-overlapped:
//  region A @0     : sx[46][80] (14720)                 stages 1-2
//                    then y1@0 y2@2880 y3@5760 (2880ea), red@8640(32)
//  region B @14720 : uL@14720 uH@21344 ([46][36], 6624ea)  stages 2-3
//                    then sP@14720 sQ@19328 ([32][36], 4608ea)
//  total 27968 B -> 5 blocks/CU (LDS-limited), 20 waves/CU.
__global__ __launch_bounds__(256, 5) void dwt_fused_k(const float* __restrict__ x,
                                                      float* __restrict__ out,
                                                      float* __restrict__ pmn,
                                                      float* __restrict__ pmx) {
    constexpr float h[8] = {H0, H1, H2, H3, H4, H5, H6, H7};
    constexpr float g[8] = {H7, -H6, H5, -H4, H3, -H2, H1, -H0};

    const int tileX = blockIdx.x;        // 0..7  -> N0 = 64*tileX
    const int tileY = blockIdx.y;        // 0..15 -> M0 = 32*tileY
    const int img = blockIdx.z;          // b*3 + c
    const int N0 = tileX * 64;
    const int M0 = tileY * 32;
    const int tid = threadIdx.x;

    __shared__ __align__(16) unsigned char smem[27968];
    float* sx = (float*)smem;                    // [46][80]
    float* y1 = (float*)smem;                    // [20][36]
    float* y2 = (float*)(smem + 2880);           // [20][36]
    float* y3 = (float*)(smem + 5760);           // [20][36]
    float* red = (float*)(smem + 8640);          // [8]
    float* uL = (float*)(smem + 14720);          // [46][36]
    float* uH = (float*)(smem + 21344);          // [46][36]
    float* sP = (float*)(smem + 14720);          // [32][36]
    float* sQ = (float*)(smem + 19328);          // [32][36]

    const float* xp = x + (size_t)img * (512 * 512);

    // ---- Stage 1: load 46x80 halo tile (base M0-7, N0-8), aligned float4 ----
    {
        const int gr0 = M0 - 7, gc0 = N0 - 8;
        for (int k = tid; k < 920; k += 256) {       // 46 rows x 20 float4
            int row = k / 20;
            int c4 = k - row * 20;
            int gr = gr0 + row;
            int gc = gc0 + 4 * c4;
            float4 v = make_float4(0.f, 0.f, 0.f, 0.f);
            if ((unsigned)gr < 512u && (unsigned)gc < 512u)
                v = *(const float4*)(xp + gr * 512 + gc);
            *(float4*)(sx + row * 80 + 4 * c4) = v;
        }
    }
    __syncthreads();

    // ---- Stage 2: row analysis. coeff col c = C0+lc, lc = 4*gq+d in [0,36) ----
    const int C0 = (N0 >> 1) - 2;
    for (int t = tid; t < 414; t += 256) {           // 46 rows x 9 col-groups
        int p = t / 9;
        int gq = t - p * 9;
        const float4* wr = (const float4*)(sx + p * 80 + 8 * gq);
        float4 w0 = wr[0], w1 = wr[1], w2 = wr[2], w3 = wr[3];
        float W[16] = {w0.x, w0.y, w0.z, w0.w, w1.x, w1.y, w1.z, w1.w,
                       w2.x, w2.y, w2.z, w2.w, w3.x, w3.y, w3.z, w3.w};
        float aL[4] = {0.f, 0.f, 0.f, 0.f}, aH[4] = {0.f, 0.f, 0.f, 0.f};
#pragma unroll
        for (int d = 0; d < 4; ++d) {
#pragma unroll
            for (int j = 0; j < 8; ++j) {
                float v = W[1 + 2 * d + j];
                aL[d] += h[j] * v;
                aH[d] += g[j] * v;
            }
            if ((unsigned)(C0 + 4 * gq + d) >= 256u) { aL[d] = 0.f; aH[d] = 0.f; }
        }
        *(float4*)(uL + p * 36 + 4 * gq) = make_float4(aL[0], aL[1], aL[2], aL[3]);
        *(float4*)(uH + p * 36 + 4 * gq) = make_float4(aH[0], aH[1], aH[2], aH[3]);
    }
    __syncthreads();

    // ---- Stage 3: column analysis. coeff row r = R0+lr, lr in [0,20) ----
    const int R0 = (M0 >> 1) - 2;
    if (tid < 180) {                                 // 20 rows x 9 col-groups
        int lr = tid / 9;
        int gq = tid - lr * 9;
        float a1[4] = {0.f, 0.f, 0.f, 0.f};
        float a2[4] = {0.f, 0.f, 0.f, 0.f};
        float a3[4] = {0.f, 0.f, 0.f, 0.f};
        if ((unsigned)(R0 + lr) < 256u) {
#pragma unroll
            for (int i = 0; i < 8; ++i) {
                float4 vH = *(const float4*)(uH + (2 * lr + i) * 36 + 4 * gq);
                float4 vL = *(const float4*)(uL + (2 * lr + i) * 36 + 4 * gq);
                a1[0] += h[i] * vH.x; a1[1] += h[i] * vH.y; a1[2] += h[i] * vH.z; a1[3] += h[i] * vH.w;
                a2[0] += g[i] * vL.x; a2[1] += g[i] * vL.y; a2[2] += g[i] * vL.z; a2[3] += g[i] * vL.w;
                a3[0] += g[i] * vH.x; a3[1] += g[i] * vH.y; a3[2] += g[i] * vH.z; a3[3] += g[i] * vH.w;
            }
        }
        *(float4*)(y1 + lr * 36 + 4 * gq) = make_float4(a1[0], a1[1], a1[2], a1[3]);
        *(float4*)(y2 + lr * 36 + 4 * gq) = make_float4(a2[0], a2[1], a2[2], a2[3]);
        *(float4*)(y3 + lr * 36 + 4 * gq) = make_float4(a3[0], a3[1], a3[2], a3[3]);
    }
    __syncthreads();

    // ---- Stage 4: column synthesis -> sP, sQ (into dead uL/uH region) ----
    for (int t = tid; t < 288; t += 256) {           // 32 rows x 9 col-groups
        int m = t / 9;
        int gq = t - m * 9;
        int mh = (m + (m & 1)) >> 1;
        int t0 = m & 1;
        float ch0 = t0 ? H1 : H0, ch1 = t0 ? H3 : H2, ch2 = t0 ? H5 : H4, ch3 = t0 ? H7 : H6;
        float cg0 = t0 ? -H6 : H7, cg1 = t0 ? -H4 : H5, cg2 = t0 ? -H2 : H3, cg3 = t0 ? -H0 : H1;
        float P[4] = {0.f, 0.f, 0.f, 0.f}, Q[4] = {0.f, 0.f, 0.f, 0.f};
#pragma unroll
        for (int k = 0; k < 4; ++k) {
            float chk = (k == 0) ? ch0 : (k == 1) ? ch1 : (k == 2) ? ch2 : ch3;
            float cgk = (k == 0) ? cg0 : (k == 1) ? cg1 : (k == 2) ? cg2 : cg3;
            float4 v1 = *(const float4*)(y1 + (mh + k) * 36 + 4 * gq);
            float4 v3 = *(const float4*)(y3 + (mh + k) * 36 + 4 * gq);
            float4 v2 = *(const float4*)(y2 + (mh + k) * 36 + 4 * gq);
            P[0] += chk * v1.x + cgk * v3.x; P[1] += chk * v1.y + cgk * v3.y;
            P[2] += chk * v1.z + cgk * v3.z; P[3] += chk * v1.w + cgk * v3.w;
            Q[0] += cgk * v2.x; Q[1] += cgk * v2.y; Q[2] += cgk * v2.z; Q[3] += cgk * v2.w;
        }
        *(float4*)(sP + m * 36 + 4 * gq) = make_float4(P[0], P[1], P[2], P[3]);
        *(float4*)(sQ + m * 36 + 4 * gq) = make_float4(Q[0], Q[1], Q[2], Q[3]);
    }
    __syncthreads();

    // ---- Stage 5: row synthesis, 8 outputs/thread, ALL 256 threads ----
    float lmn = 3.4e38f, lmx = -3.4e38f;
    {
        int m = tid >> 3;                            // 0..31
        int qq = tid & 7;                            // cols 8*qq .. 8*qq+7
        const float* pp = sP + m * 36 + 4 * qq;
        const float* qp = sQ + m * 36 + 4 * qq;
        float4 pa = *(const float4*)pp, pb = *(const float4*)(pp + 4);
        float4 qa = *(const float4*)qp, qb = *(const float4*)(qp + 4);
        float sp[8] = {pa.x, pa.y, pa.z, pa.w, pb.x, pb.y, pb.z, pb.w};
        float sq[8] = {qa.x, qa.y, qa.z, qa.w, qb.x, qb.y, qb.z, qb.w};
        float val[8];
#pragma unroll
        for (int e = 0; e < 8; ++e) {
            const int t0 = e & 1;
            const int r0 = (e + (e & 1)) >> 1;
            float r = g[t0] * sp[r0] + g[t0 + 2] * sp[r0 + 1] + g[t0 + 4] * sp[r0 + 2] + g[t0 + 6] * sp[r0 + 3]
                    + h[t0] * sq[r0] + h[t0 + 2] * sq[r0 + 1] + h[t0 + 4] * sq[r0 + 2] + h[t0 + 6] * sq[r0 + 3];
            val[e] = r;
            lmn = fminf(lmn, r);
            lmx = fmaxf(lmx, r);
        }
        float* op = out + ((size_t)img * 512 + (M0 + m)) * 512 + (N0 + 8 * qq);
        *(float4*)op = make_float4(val[0], val[1], val[2], val[3]);
        *(float4*)(op + 4) = make_float4(val[4], val[5], val[6], val[7]);
    }

    // block reduce -> one partial pair per block (distinct addresses, no atomics)
#pragma unroll
    for (int off = 32; off > 0; off >>= 1) {
        lmn = fminf(lmn, __shfl_down(lmn, off));
        lmx = fmaxf(lmx, __shfl_down(lmx, off));
    }
    int wv = tid >> 6;
    if ((tid & 63) == 0) { red[wv] = lmn; red[4 + wv] = lmx; }
    __syncthreads();
    if (tid == 0) {
        float mn = fminf(fminf(red[0], red[1]), fminf(red[2], red[3]));
        float mx = fmaxf(fmaxf(red[4], red[5]), fmaxf(red[6], red[7]));
        int blin = (img * 16 + tileY) * 8 + tileX;   // 0..12287
        pmn[blin] = mn;
        pmx[blin] = mx;
    }
}

// 3072 blocks: block b -> sample s = b/96, chunk k = b%96.
// Phase 1: reduce the sample's 384 partials (L2-hot) to block-uniform mn/mx.
// Phase 2: normalize 2048 float4 (s*196608 + k*2048 ... +2048).
__global__ __launch_bounds__(256) void normalize_k(float* __restrict__ out,
                                                   const float* __restrict__ pmn,
                                                   const float* __restrict__ pmx) {
    __shared__ float r[8];
    __shared__ float bc[2];
    const int b = blockIdx.x;
    const int s = b / 96;
    const int chunk = b - s * 96;
    const int tid = threadIdx.x;

    float lmn = 3.4e38f, lmx = -3.4e38f;
    const int base = s * 384;
    for (int j = tid; j < 384; j += 256) {
        lmn = fminf(lmn, pmn[base + j]);
        lmx = fmaxf(lmx, pmx[base + j]);
    }
#pragma unroll
    for (int off = 32; off > 0; off >>= 1) {
        lmn = fminf(lmn, __shfl_down(lmn, off));
        lmx = fmaxf(lmx, __shfl_down(lmx, off));
    }
    int wv = tid >> 6;
    if ((tid & 63) == 0) { r[wv] = lmn; r[4 + wv] = lmx; }
    __syncthreads();
    if (tid == 0) {
        bc[0] = fminf(fminf(r[0], r[1]), fminf(r[2], r[3]));
        bc[1] = fmaxf(fmaxf(r[4], r[5]), fmaxf(r[6], r[7]));
    }
    __syncthreads();
    const float mn = bc[0];
    const float inv = 1.0f / (bc[1] - mn + 1e-8f);

    float4* o4 = (float4*)out;
    const size_t base4 = (size_t)s * 196608 + (size_t)chunk * 2048;
#pragma unroll
    for (int it = 0; it < 8; ++it) {
        size_t i = base4 + it * 256 + tid;
        float4 v = o4[i];
        v.x = (v.x - mn) * inv;
        v.y = (v.y - mn) * inv;
        v.z = (v.z - mn) * inv;
        v.w = (v.w - mn) * inv;
        o4[i] = v;
    }
}

extern "C" void kernel_launch(void* const* d_in, const int* in_sizes, int n_in,
                              void* d_out, int out_size, void* d_ws, size_t ws_size,
                              hipStream_t stream) {
    const float* x = (const float*)d_in[0];
    float* out = (float*)d_out;
    float* wsf = (float*)d_ws;
    float* pmn = wsf;                 // 12288
    float* pmx = wsf + 12288;         // 12288

    hipLaunchKernelGGL(dwt_fused_k, dim3(8, 16, 96), dim3(256), 0, stream, x, out, pmn, pmx);
    hipLaunchKernelGGL(normalize_k, dim3(3072), dim3(256), 0, stream, out, pmn, pmx);
}